// Round 3
// baseline (193.065 us; speedup 1.0000x reference)
//
#include <hip/hip_runtime.h>
#include <math.h>

// Problem constants (match reference)
#define B_   16
#define C_   256
#define H_   96
#define W_   128
#define OH_  12
#define OW_  16
#define N_   192          // OH*OW
#define HID_ 128
#define Q_   4
#define PIX_ (H_*W_)      // 12288

typedef __attribute__((ext_vector_type(8))) short short8;
typedef __attribute__((ext_vector_type(4))) float f32x4;

__device__ __forceinline__ ushort f2bf(float f) {
    union { float f; unsigned u; } v; v.f = f;
    unsigned r = (v.u + 0x7FFFu + ((v.u >> 16) & 1u)) >> 16;  // RNE
    return (ushort)r;
}

// ---------------------------------------------------------------------------
// Kernel 1: fused avgpool(8x8) + pairwise soft-rank + soft-quantile weights
// ---------------------------------------------------------------------------
__device__ __forceinline__ float block_max_192(float v, volatile float* red, int t) {
    #pragma unroll
    for (int o = 32; o; o >>= 1) v = fmaxf(v, __shfl_down(v, o, 64));
    __syncthreads();
    if ((t & 63) == 0) red[t >> 6] = v;
    __syncthreads();
    return fmaxf(fmaxf(red[0], red[1]), red[2]);
}

__device__ __forceinline__ float block_sum_192(float v, volatile float* red, int t) {
    #pragma unroll
    for (int o = 32; o; o >>= 1) v += __shfl_down(v, o, 64);
    __syncthreads();
    if ((t & 63) == 0) red[t >> 6] = v;
    __syncthreads();
    return red[0] + red[1] + red[2];
}

__global__ __launch_bounds__(192)
void quantile_kernel(const float* __restrict__ x, float* __restrict__ qvals) {
    const int c = blockIdx.x;
    const int b = blockIdx.y;
    const int t = threadIdx.x;

    __shared__ float fv[N_];
    __shared__ float red[3];

    const float* plane = x + (size_t)(b * C_ + c) * PIX_;

    const int oh = t >> 4, ow = t & 15;
    const float* p0 = plane + oh * 8 * W_ + ow * 8;
    float s = 0.f;
    #pragma unroll
    for (int r = 0; r < 8; ++r) {
        float4 a = *reinterpret_cast<const float4*>(p0 + r * W_);
        float4 d = *reinterpret_cast<const float4*>(p0 + r * W_ + 4);
        s += a.x + a.y + a.z + a.w + d.x + d.y + d.z + d.w;
    }
    const float fi = s * (1.0f / 64.0f);
    fv[t] = fi;
    __syncthreads();

    float r_i = 1.0f;
    for (int j = 0; j < N_; ++j) {
        float d = (fi - fv[j]) * 10.0f;
        r_i += __builtin_amdgcn_rcpf(1.0f + __expf(-d));
    }

    const float tgts[Q_] = {48.75f, 96.5f, 144.25f, 182.45f};
    #pragma unroll
    for (int q = 0; q < Q_; ++q) {
        float lg  = -fabsf(r_i - tgts[q]) * 10.0f;
        float mx  = block_max_192(lg, red, t);
        float e   = __expf(lg - mx);
        float se  = block_sum_192(e, red, t);
        float swf = block_sum_192(e * fi, red, t);
        if (t == 0) qvals[(size_t)(b * C_ + c) * Q_ + q] = swf / se;
    }
}

// ---------------------------------------------------------------------------
// Kernel 2: tiny MLP per batch -> scale[b,c]
// ---------------------------------------------------------------------------
__global__ __launch_bounds__(256)
void mlp_kernel(const float* __restrict__ qvals, const float* __restrict__ w1,
                const float* __restrict__ w2, float* __restrict__ scale) {
    const int b = blockIdx.x;
    const int t = threadIdx.x;

    __shared__ float ql[C_ * Q_];
    __shared__ float tl[HID_ * Q_];

    for (int i = t; i < C_ * Q_; i += 256) ql[i] = qvals[(size_t)b * C_ * Q_ + i];
    __syncthreads();

    #pragma unroll
    for (int rep = 0; rep < 2; ++rep) {
        int idx = rep * 256 + t;
        int h = idx >> 2, q = idx & 3;
        float acc = 0.f;
        for (int cc = 0; cc < C_; ++cc) acc += w1[h * C_ + cc] * ql[(cc << 2) + q];
        tl[idx] = fmaxf(acc, 0.f);
    }
    __syncthreads();

    float acc = 0.f;
    const float* w2r = w2 + (size_t)t * (HID_ * Q_);
    for (int i = 0; i < HID_ * Q_; ++i) acc += w2r[i] * tl[i];
    scale[(size_t)b * C_ + t] = __builtin_amdgcn_rcpf(1.0f + __expf(-acc));
}

// ---------------------------------------------------------------------------
// Kernel 2b: build M_b[c,k] = wf[c,k] + wf[c,C+k]*scale[b,k] in bf16 (to ws)
// ---------------------------------------------------------------------------
__global__ __launch_bounds__(256)
void buildM_kernel(const float* __restrict__ wf, const float* __restrict__ scale,
                   ushort* __restrict__ M) {
    const int idx = (blockIdx.x * 256 + threadIdx.x) * 8;   // into [B][C][256]
    const int b  = idx >> 16;
    const int c  = (idx >> 8) & 255;
    const int k0 = idx & 255;
    const float* w = wf + (size_t)c * (2 * C_);
    float4 a0 = *reinterpret_cast<const float4*>(w + k0);
    float4 a1 = *reinterpret_cast<const float4*>(w + k0 + 4);
    float4 g0 = *reinterpret_cast<const float4*>(w + C_ + k0);
    float4 g1 = *reinterpret_cast<const float4*>(w + C_ + k0 + 4);
    const float* sc = scale + b * C_ + k0;
    float4 s0 = *reinterpret_cast<const float4*>(sc);
    float4 s1 = *reinterpret_cast<const float4*>(sc + 4);
    short8 r;
    r[0] = (short)f2bf(a0.x + g0.x * s0.x);
    r[1] = (short)f2bf(a0.y + g0.y * s0.y);
    r[2] = (short)f2bf(a0.z + g0.z * s0.z);
    r[3] = (short)f2bf(a0.w + g0.w * s0.w);
    r[4] = (short)f2bf(a1.x + g1.x * s1.x);
    r[5] = (short)f2bf(a1.y + g1.y * s1.y);
    r[6] = (short)f2bf(a1.z + g1.z * s1.z);
    r[7] = (short)f2bf(a1.w + g1.w * s1.w);
    *reinterpret_cast<short8*>(M + idx) = r;
}

// ---------------------------------------------------------------------------
// Kernel 3 (MFMA v2): out[b] = M_b @ X_b, bf16 inputs / fp32 accumulate.
// Block: 512 threads (8 waves). Tile: full 256 c x 64 p, whole K=256 staged.
// Staging: register transpose (8 coalesced dword loads down k per thread),
// one XOR-swizzled ds_write_b128 into Bt[p][k]. ONE barrier per block, then
// 64 MFMAs/wave with conflict-free swizzled ds_read_b128 B-frags and L2-hot
// A-frags direct from the precomputed bf16 M.
// Swizzle: byte = p*512 + (k*2 ^ ((p&7)<<4))  -- same involution on both sides.
// ---------------------------------------------------------------------------
#define GBN 64

__global__ __launch_bounds__(512)
void mfma_fuse_kernel(const float* __restrict__ x, const ushort* __restrict__ M,
                      float* __restrict__ out) {
    const int b  = blockIdx.y;
    const int pB = blockIdx.x * GBN;
    const int t  = threadIdx.x;
    const int wave = t >> 6, lane = t & 63;
    const int lr = lane & 15, lg = lane >> 4;

    __shared__ __align__(16) ushort Bt[GBN * 256];   // [p][k] swizzled, 32 KB

    const size_t xb = (size_t)b * C_ * PIX_ + pB;
    const short* Mb = (const short*)(M + (size_t)b * C_ * C_);

    // ---- staging: thread owns p = t&63; k-rows wave*8 + cc*64 + j ----
    const int sp  = t & 63;
    const int sk0 = wave * 8;
    #pragma unroll
    for (int cc = 0; cc < 4; ++cc) {
        const int kr = cc * 64 + sk0;
        const float* src = x + xb + (size_t)kr * PIX_ + sp;
        float v[8];
        #pragma unroll
        for (int j = 0; j < 8; ++j) v[j] = src[(size_t)j * PIX_];
        short8 pk;
        #pragma unroll
        for (int j = 0; j < 8; ++j) pk[j] = (short)f2bf(v[j]);
        *reinterpret_cast<short8*>(
            (char*)Bt + (sp * 512 + ((kr * 2) ^ ((sp & 7) << 4)))) = pk;
    }
    __syncthreads();

    // ---- MFMA: wave owns 32 c (2 cfrags) x 64 p (4 pfrags), K=256 ----
    const int c0 = wave * 32;
    f32x4 acc[2][4] = {};
    #pragma unroll
    for (int ks = 0; ks < 8; ++ks) {
        const int ko = ks * 32 + lg * 8;
        short8 a0 = *reinterpret_cast<const short8*>(Mb + (size_t)(c0 + lr) * C_ + ko);
        short8 a1 = *reinterpret_cast<const short8*>(Mb + (size_t)(c0 + 16 + lr) * C_ + ko);
        #pragma unroll
        for (int pf = 0; pf < 4; ++pf) {
            const int p = pf * 16 + lr;
            short8 bv = *reinterpret_cast<const short8*>(
                (const char*)Bt + (p * 512 + ((ko * 2) ^ ((p & 7) << 4))));
            acc[0][pf] = __builtin_amdgcn_mfma_f32_16x16x32_bf16(a0, bv, acc[0][pf], 0, 0, 0);
            acc[1][pf] = __builtin_amdgcn_mfma_f32_16x16x32_bf16(a1, bv, acc[1][pf], 0, 0, 0);
        }
    }

    // ---- epilogue: C/D layout col=lane&15, row=(lane>>4)*4+reg ----
    #pragma unroll
    for (int cf = 0; cf < 2; ++cf) {
        #pragma unroll
        for (int pf = 0; pf < 4; ++pf) {
            #pragma unroll
            for (int r = 0; r < 4; ++r) {
                const int c = c0 + cf * 16 + lg * 4 + r;
                out[(size_t)(b * C_ + c) * PIX_ + pB + pf * 16 + lr] = acc[cf][pf][r];
            }
        }
    }
}

// ---------------------------------------------------------------------------
// Kernel 3 fallback (fp32): used only if ws_size can't hold M.
// ---------------------------------------------------------------------------
#define BM 64
#define BN 64
#define BK 16

__global__ __launch_bounds__(256)
void fuse_kernel(const float* __restrict__ x, const float* __restrict__ wf,
                 const float* __restrict__ scale, float* __restrict__ out) {
    const int pB = blockIdx.x * BN;
    const int cB = blockIdx.y * BM;
    const int b  = blockIdx.z;
    const int t  = threadIdx.x;

    __shared__ float Ms[BM][BK + 1];
    __shared__ float Xs[BK][BN];
    __shared__ float sc[C_];

    sc[t] = scale[(size_t)b * C_ + t];
    __syncthreads();

    float acc[4][4] = {};
    const int tx = t & 15, ty = t >> 4;
    const size_t xbase = (size_t)b * C_ * PIX_ + pB;

    for (int kb = 0; kb < C_; kb += BK) {
        #pragma unroll
        for (int i = 0; i < 4; ++i) {
            int li = t + i * 256;
            int cl = li >> 4, kl = li & 15;
            int cg = cB + cl, kg = kb + kl;
            Ms[cl][kl] = wf[(size_t)cg * 512 + kg]
                       + wf[(size_t)cg * 512 + 256 + kg] * sc[kg];
        }
        #pragma unroll
        for (int i = 0; i < 4; ++i) {
            int li = t + i * 256;
            int kl = li >> 6, pl = li & 63;
            Xs[kl][pl] = x[xbase + (size_t)(kb + kl) * PIX_ + pl];
        }
        __syncthreads();

        #pragma unroll
        for (int kk = 0; kk < BK; ++kk) {
            float av[4];
            #pragma unroll
            for (int j = 0; j < 4; ++j) av[j] = Ms[ty * 4 + j][kk];
            float4 bv = *reinterpret_cast<const float4*>(&Xs[kk][tx * 4]);
            float bvv[4] = {bv.x, bv.y, bv.z, bv.w};
            #pragma unroll
            for (int i = 0; i < 4; ++i)
                #pragma unroll
                for (int j = 0; j < 4; ++j)
                    acc[i][j] += av[i] * bvv[j];
        }
        __syncthreads();
    }

    #pragma unroll
    for (int i = 0; i < 4; ++i) {
        float4 v = make_float4(acc[i][0], acc[i][1], acc[i][2], acc[i][3]);
        *reinterpret_cast<float4*>(
            out + (size_t)(b * C_ + cB + ty * 4 + i) * PIX_ + pB + tx * 4) = v;
    }
}

// ---------------------------------------------------------------------------
extern "C" void kernel_launch(void* const* d_in, const int* in_sizes, int n_in,
                              void* d_out, int out_size, void* d_ws, size_t ws_size,
                              hipStream_t stream) {
    const float* x  = (const float*)d_in[0];   // [B,C,H,W]
    const float* w1 = (const float*)d_in[1];   // [HID,C]
    const float* w2 = (const float*)d_in[2];   // [C,HID,Q]
    const float* wf = (const float*)d_in[3];   // [C,2C]
    float* out = (float*)d_out;

    float*  ws_qvals = (float*)d_ws;                      // 16384 f
    float*  ws_scale = ws_qvals + (B_ * C_ * Q_);         // 4096 f
    ushort* ws_M     = (ushort*)(ws_scale + B_ * C_);     // 1M bf16 = 2MB
    const size_t need = (size_t)(B_ * C_ * Q_ + B_ * C_) * 4
                      + (size_t)B_ * C_ * C_ * 2;

    dim3 g1(C_, B_);
    quantile_kernel<<<g1, 192, 0, stream>>>(x, ws_qvals);
    mlp_kernel<<<B_, 256, 0, stream>>>(ws_qvals, w1, w2, ws_scale);

    if (ws_size >= need) {
        buildM_kernel<<<(B_ * C_ * C_) / (256 * 8), 256, 0, stream>>>(wf, ws_scale, ws_M);
        dim3 g3(PIX_ / GBN, B_);
        mfma_fuse_kernel<<<g3, 512, 0, stream>>>(x, ws_M, out);
    } else {
        dim3 g3(PIX_ / BN, C_ / BM, B_);
        fuse_kernel<<<g3, 256, 0, stream>>>(x, wf, ws_scale, out);
    }
}